// Round 10
// baseline (450.815 us; speedup 1.0000x reference)
//
#include <hip/hip_runtime.h>

#define KDIM 128
#define NNODE 50000
#define CHSTRIDE 800000   // floats per chunk slab: 50000 nodes * 16 feats

typedef _Float16 f16x8 __attribute__((ext_vector_type(8)));
typedef _Float16 f16x4 __attribute__((ext_vector_type(4)));
typedef float f32x16 __attribute__((ext_vector_type(16)));

// ---------------------------------------------------------------------------
// CSR build. hist/scatter are XCD-chunked: block = (chunk<<3)|r, node-range r
// on (round-robin-dispatched) XCD r -> cnt/cursor atomics and col writes stay
// XCD-L2-local.
// ---------------------------------------------------------------------------
#define NRANGE 6250   // 50000 / 8
#define ECHUNK 3200   // edges per chunk; chunks = ceil(E/3200) = 250

__global__ void hist_kernel(const int* __restrict__ src, int* __restrict__ cnt, int E) {
    const int r = blockIdx.x & 7;
    const int chunk = blockIdx.x >> 3;
    const int lo = r * NRANGE, hi = lo + NRANGE;
    const int base = chunk * ECHUNK;
    const int end = min(base + ECHUNK, E);
    for (int i = base + threadIdx.x; i < end; i += 256) {
        int s = src[i];
        if (s >= lo && s < hi) atomicAdd(&cnt[s], 1);
    }
}

__global__ void scatter_kernel(const int* __restrict__ src, const int* __restrict__ dst,
                               int* cursor, int* __restrict__ col, int E) {
    const int r = blockIdx.x & 7;
    const int chunk = blockIdx.x >> 3;
    const int lo = r * NRANGE, hi = lo + NRANGE;
    const int base = chunk * ECHUNK;
    const int end = min(base + ECHUNK, E);
    for (int i = base + threadIdx.x; i < end; i += 256) {
        int s = src[i];
        if (s >= lo && s < hi) {
            int p = atomicAdd(&cursor[s], 1);
            col[p] = dst[i];
        }
    }
}

// Hierarchical exclusive scan of cnt[0..N) -> row_ptr, cursor (3 kernels).
__global__ void scan1_kernel(const int* __restrict__ cnt, int* __restrict__ row_ptr,
                             int* __restrict__ bsum, int N) {
    __shared__ int ws[4];
    const int t = threadIdx.x;
    const int lane = t & 63, w = t >> 6;
    const int i = blockIdx.x * 256 + t;
    int v = (i < N) ? cnt[i] : 0;
    int x = v;
    #pragma unroll
    for (int off = 1; off < 64; off <<= 1) {
        int u = __shfl_up(x, off);
        if (lane >= off) x += u;
    }
    if (lane == 63) ws[w] = x;
    __syncthreads();
    int wexcl = 0;
    #pragma unroll
    for (int k = 0; k < 4; k++) wexcl += (k < w) ? ws[k] : 0;
    if (i < N) row_ptr[i] = wexcl + x - v;      // block-local exclusive
    if (t == 255) bsum[blockIdx.x] = wexcl + x; // block total
}

__global__ void scan2_kernel(int* __restrict__ bsum, int NB) {
    __shared__ int ws[4];
    const int t = threadIdx.x;
    const int lane = t & 63, w = t >> 6;
    int v = (t < NB) ? bsum[t] : 0;
    int x = v;
    #pragma unroll
    for (int off = 1; off < 64; off <<= 1) {
        int u = __shfl_up(x, off);
        if (lane >= off) x += u;
    }
    if (lane == 63) ws[w] = x;
    __syncthreads();
    int wexcl = 0;
    #pragma unroll
    for (int k = 0; k < 4; k++) wexcl += (k < w) ? ws[k] : 0;
    if (t < NB) bsum[t] = wexcl + x - v;        // exclusive block offsets
}

__global__ void scan3_kernel(const int* __restrict__ bsum, int* __restrict__ row_ptr,
                             int* __restrict__ cursor, int N, int E) {
    const int i = blockIdx.x * 256 + threadIdx.x;
    if (i < N) {
        int v = row_ptr[i] + bsum[blockIdx.x];
        row_ptr[i] = v;
        cursor[i] = v;
    }
    if (i == 0) row_ptr[N] = E;
}

// Sort each CSR row's col values ascending -> deterministic summation order.
__global__ void sortrows_kernel(const int* __restrict__ row_ptr, int* __restrict__ col, int M) {
    int wid = (blockIdx.x * blockDim.x + threadIdx.x) >> 6;
    int lane = threadIdx.x & 63;
    if (wid >= M) return;
    int s = row_ptr[wid], e = row_ptr[wid + 1], len = e - s;
    if (len <= 1) return;
    if (len <= 64) {
        int v = (lane < len) ? col[s + lane] : 0x7fffffff;
        #pragma unroll
        for (int k = 2; k <= 64; k <<= 1) {
            #pragma unroll
            for (int j = k >> 1; j > 0; j >>= 1) {
                int o = __shfl_xor(v, j);
                bool dir = ((lane & k) == 0);
                bool smaller = ((lane & j) == 0);
                int mn = min(v, o), mx = max(v, o);
                v = (dir == smaller) ? mn : mx;
            }
        }
        if (lane < len) col[s + lane] = v;
    } else if (lane == 0) {
        for (int a = s + 1; a < e; a++) {
            int key = col[a];
            int b = a - 1;
            while (b >= s && col[b] > key) { col[b + 1] = col[b]; b--; }
            col[b + 1] = key;
        }
    }
}

// ---------------------------------------------------------------------------
// MaxK: keep top-32 of 128 per row (jax.lax.top_k tie-break: lower index wins)
// Writes hs in CHUNKED layout [chunk=f/16][node][16] (64B per node per chunk)
// so the aggregate gather is XCD-L2-resident per chunk.
// ---------------------------------------------------------------------------
__global__ void maxk_kernel(const float* __restrict__ h, float* __restrict__ hsc, int M) {
    int wid = (blockIdx.x * blockDim.x + threadIdx.x) >> 6;
    int lane = threadIdx.x & 63;
    if (wid >= M) return;
    float2 v = ((const float2*)(h + (size_t)wid * KDIM))[lane];

    unsigned int u0 = __float_as_uint(v.x);
    u0 = (u0 & 0x80000000u) ? ~u0 : (u0 | 0x80000000u);
    unsigned int u1 = __float_as_uint(v.y);
    u1 = (u1 & 0x80000000u) ? ~u1 : (u1 | 0x80000000u);

    unsigned int prefix = 0;
    int remaining = 32;
    #pragma unroll
    for (int b = 31; b >= 0; --b) {
        unsigned int candHi = (prefix >> b) | 1u;
        unsigned long long m0 = __ballot((u0 >> b) == candHi);
        unsigned long long m1 = __ballot((u1 >> b) == candHi);
        int cnt = __popcll(m0) + __popcll(m1);
        if (cnt >= remaining) prefix |= (1u << b);
        else remaining -= cnt;
    }

    unsigned long long e0 = __ballot(u0 == prefix);
    unsigned long long e1 = __ballot(u1 == prefix);
    unsigned long long g0 = __ballot(u0 > prefix);
    unsigned long long g1 = __ballot(u1 > prefix);
    int quota = 32 - (__popcll(g0) + __popcll(g1));
    unsigned long long below = (1ULL << lane) - 1ULL;
    int rank0 = __popcll(e0 & below) + __popcll(e1 & below);
    int rank1 = rank0 + (int)((e0 >> lane) & 1ULL);
    bool k0 = (u0 > prefix) || (((e0 >> lane) & 1ULL) && rank0 < quota);
    bool k1 = (u1 > prefix) || (((e1 >> lane) & 1ULL) && rank1 < quota);

    float2 o;
    o.x = k0 ? v.x : 0.0f;
    o.y = k1 ? v.y : 0.0f;
    // lane owns features 2l,2l+1 -> chunk = l>>3, float2 slot = l&7
    ((float2*)(hsc + (size_t)(lane >> 3) * CHSTRIDE))[(size_t)wid * 8 + (lane & 7)] = o;
}

// ---------------------------------------------------------------------------
// Aggregation (feature-chunked): agg[n, c*16..c*16+15] = sum over row n of
// hsc[c][col][*] / (deg+1e-6).  chunk c = blockIdx&7 -> one chunk per XCD
// (round-robin heuristic): each XCD's gathers hit its 3.2MB L2-resident slab.
// Lane = (e8 = lane>>3 edge slot, f2 = lane&7 feature pair): 8 edges x 64B
// in flight; fixed shfl-xor tree (commutative pairs) -> deterministic.
// ---------------------------------------------------------------------------
#define NPB 32   // nodes per block (4 waves x 8 nodes)
__global__ __launch_bounds__(256)
void aggregate_kernel(const float* __restrict__ hsc, const int* __restrict__ row_ptr,
                      const int* __restrict__ col, float* __restrict__ agg, int M) {
    const int c = blockIdx.x & 7;
    const int g = blockIdx.x >> 3;
    const int w = threadIdx.x >> 6;
    const int lane = threadIdx.x & 63;
    const int e8 = lane >> 3;
    const int f2 = lane & 7;
    const float2* __restrict__ hp = (const float2*)(hsc + (size_t)c * CHSTRIDE);

    const int n0 = g * NPB + w * 8;
    #pragma unroll 1
    for (int u = 0; u < 8; u++) {
        int n = n0 + u;
        if (n >= M) break;
        int s = row_ptr[n], e = row_ptr[n + 1];
        float2 a0 = make_float2(0.f, 0.f), a1 = a0;
        int j = s + e8;
        for (; j + 8 < e; j += 16) {
            float2 v0 = hp[(size_t)col[j] * 8 + f2];
            float2 v1 = hp[(size_t)col[j + 8] * 8 + f2];
            a0.x += v0.x; a0.y += v0.y;
            a1.x += v1.x; a1.y += v1.y;
        }
        if (j < e) { float2 v = hp[(size_t)col[j] * 8 + f2]; a0.x += v.x; a0.y += v.y; }
        float2 t;
        t.x = a0.x + a1.x; t.y = a0.y + a1.y;
        t.x += __shfl_xor(t.x, 8);  t.y += __shfl_xor(t.y, 8);
        t.x += __shfl_xor(t.x, 16); t.y += __shfl_xor(t.y, 16);
        t.x += __shfl_xor(t.x, 32); t.y += __shfl_xor(t.y, 32);
        if (e8 == 0) {
            float inv = 1.0f / ((float)(e - s) + 1e-6f);
            float2 o;
            o.x = t.x * inv; o.y = t.y * inv;
            ((float2*)(agg + (size_t)n * KDIM + c * 16))[f2] = o;
        }
    }
}

// ---------------------------------------------------------------------------
// Weight prep: transpose to [n][k] and split f32 -> fp16 (hi, lo).
// ---------------------------------------------------------------------------
__global__ void conv_wt_kernel(const float* __restrict__ W_in,
                               const float* __restrict__ W_self,
                               const float* __restrict__ W_neigh,
                               const float* __restrict__ W_out,
                               _Float16* __restrict__ wb) {
    int t = blockIdx.x * blockDim.x + threadIdx.x;
    if (t < 81920) {
        int m = t >> 14;            // 0..4
        int e = t & 16383;
        int n = e >> 7, k = e & 127;
        const float* S = (m == 0) ? W_in
                       : (m <= 2) ? (W_self + (size_t)(m - 1) * 16384)
                                  : (W_neigh + (size_t)(m - 3) * 16384);
        float v = S[k * 128 + n];
        _Float16 hi = (_Float16)v;
        _Float16 lo = (_Float16)(v - (float)hi);
        int pair = m * 2;
        wb[(size_t)pair * 16384 + n * 128 + k] = hi;
        wb[(size_t)(pair + 1) * 16384 + n * 128 + k] = lo;
    } else if (t < 90112) {
        int e = t - 81920;          // [0, 8192)
        int n = e >> 7, k = e & 127;
        float v = W_out[k * 64 + n];
        _Float16 hi = (_Float16)v;
        _Float16 lo = (_Float16)(v - (float)hi);
        wb[(size_t)10 * 16384 + e] = hi;
        wb[(size_t)11 * 16384 + e] = lo;
    }
}

// ---------------------------------------------------------------------------
// Split-fp16 MFMA GEMM: C[M,BN] = A1 @ B1 (+ A2 @ B2) (+ bias), K=128, f32 I/O.
// a@b = hi@hi + hi@lo + lo@hi (lo@lo dropped, ~2^-22 rel).
// Sources staged SEQUENTIALLY through one 32 KB LDS buffer.
// A1CHUNK: A1 is in chunked layout [k/16][node][16] (hs from maxk).
// ---------------------------------------------------------------------------
template <int BN, bool DUAL, bool BIAS, bool A1CHUNK>
__global__ __launch_bounds__(256)
void gemm_mfma(const float* __restrict__ A1, const float* __restrict__ A2,
               const _Float16* __restrict__ B1h, const _Float16* __restrict__ B1l,
               const _Float16* __restrict__ B2h, const _Float16* __restrict__ B2l,
               const float* __restrict__ bias, float* __restrict__ C, int M) {
    constexpr int NSRC = DUAL ? 2 : 1;
    constexpr int NT = BN / 32;
    constexpr int TPW = NT / 2;

    __shared__ __align__(16) char Alds[2 * 64 * 256];  // 32 KB: [h/l][row][256B]

    const int tid = threadIdx.x;
    const int w = tid >> 6;
    const int lane = tid & 63;
    const int l31 = lane & 31;
    const int kslot = lane >> 5;
    const int row0 = blockIdx.x * 64;

    const int n0 = (BN == 128) ? w * 32 : (w & 1) * 32;
    const int mt0 = (BN == 128) ? 0 : (w >> 1);

    f32x16 acc[TPW];
    #pragma unroll
    for (int t = 0; t < TPW; t++)
        #pragma unroll
        for (int e = 0; e < 16; e++) acc[t][e] = 0.0f;

    for (int s = 0; s < NSRC; s++) {
        if (s) __syncthreads();   // previous source's MFMA reads done
        // ---- stage A_s: f32 -> (hi,lo) fp16 into swizzled LDS ----
        const float* A = s ? A2 : A1;
        #pragma unroll
        for (int p = 0; p < 8; p++) {
            int idx = tid + p * 256;
            int row = idx >> 5, k4 = idx & 31;
            float4 v = make_float4(0.f, 0.f, 0.f, 0.f);
            if (row0 + row < M) {
                if (A1CHUNK && s == 0)
                    v = *(const float4*)(A + (size_t)(k4 >> 2) * CHSTRIDE
                                           + (size_t)(row0 + row) * 16 + (k4 & 3) * 4);
                else
                    v = *(const float4*)(A + (size_t)(row0 + row) * KDIM + k4 * 4);
            }
            _Float16 h0 = (_Float16)v.x, h1 = (_Float16)v.y,
                     h2 = (_Float16)v.z, h3 = (_Float16)v.w;
            f16x4 hv = {h0, h1, h2, h3};
            f16x4 lv = {(_Float16)(v.x - (float)h0), (_Float16)(v.y - (float)h1),
                        (_Float16)(v.z - (float)h2), (_Float16)(v.w - (float)h3)};
            int boff = (k4 * 8) ^ ((row & 7) << 4);
            *(f16x4*)(Alds + row * 256 + boff) = hv;
            *(f16x4*)(Alds + 16384 + row * 256 + boff) = lv;
        }
        __syncthreads();

        // ---- K-loop ----
        const _Float16* Bh = s ? B2h : B1h;
        const _Float16* Bl = s ? B2l : B1l;
        const _Float16* bph = Bh + (size_t)(n0 + l31) * 128 + kslot * 8;
        const _Float16* bpl = Bl + (size_t)(n0 + l31) * 128 + kslot * 8;
        #pragma unroll
        for (int kb = 0; kb < 8; kb++) {
            f16x8 bh = *(const f16x8*)(bph + kb * 16);
            f16x8 bl = *(const f16x8*)(bpl + kb * 16);
            #pragma unroll
            for (int t = 0; t < TPW; t++) {
                int row = (mt0 + t) * 32 + l31;
                int boff = ((kb * 2 + kslot) * 16) ^ ((row & 7) << 4);
                const char* rp = Alds + row * 256 + boff;
                f16x8 ah = *(const f16x8*)(rp);
                f16x8 al = *(const f16x8*)(rp + 16384);
                acc[t] = __builtin_amdgcn_mfma_f32_32x32x16_f16(al, bh, acc[t], 0, 0, 0);
                acc[t] = __builtin_amdgcn_mfma_f32_32x32x16_f16(ah, bl, acc[t], 0, 0, 0);
                acc[t] = __builtin_amdgcn_mfma_f32_32x32x16_f16(ah, bh, acc[t], 0, 0, 0);
            }
        }
    }

    float bv = 0.0f;
    if (BIAS) bv = bias[n0 + l31];
    #pragma unroll
    for (int t = 0; t < TPW; t++) {
        #pragma unroll
        for (int r = 0; r < 16; r++) {
            int row = row0 + (mt0 + t) * 32 + (r & 3) + 8 * (r >> 2) + 4 * kslot;
            if (row < M) C[(size_t)row * BN + n0 + l31] = acc[t][r] + bv;
        }
    }
}

// ---------------------------------------------------------------------------
extern "C" void kernel_launch(void* const* d_in, const int* in_sizes, int n_in,
                              void* d_out, int out_size, void* d_ws, size_t ws_size,
                              hipStream_t stream) {
    const float* x       = (const float*)d_in[0];
    const float* W_in    = (const float*)d_in[1];
    const float* b_in    = (const float*)d_in[2];
    const float* W_self  = (const float*)d_in[3];
    const float* W_neigh = (const float*)d_in[4];
    const float* W_out   = (const float*)d_in[5];
    const float* b_out   = (const float*)d_in[6];
    const int*   eidx    = (const int*)d_in[7];

    const int N = NNODE, E = 800000;
    const int* src = eidx;
    const int* dst = eidx + E;

    char* ws = (char*)d_ws;
    float* h   = (float*)(ws);                  // 25.6 MB
    float* hsc = (float*)(ws + 25600000);       // 25.6 MB (chunked [8][N][16])
    float* agg = (float*)(ws + 51200000);       // 25.6 MB
    int* cnt     = (int*)(ws + 76800000);       // 200 KB
    int* row_ptr = (int*)(ws + 77000000);       // 200 KB
    int* cursor  = (int*)(ws + 77200016);       // 200 KB
    int* col     = (int*)(ws + 77400016);       // 3.2 MB
    _Float16* wb = (_Float16*)(ws + 80600016);  // 384 KB weight slots
    int* bsum    = (int*)(ws + 81000016);       // 1 KB scan block sums

    const _Float16* WinT_h  = wb + (size_t)0 * 16384;
    const _Float16* WinT_l  = wb + (size_t)1 * 16384;
    const _Float16* WoutT_h = wb + (size_t)10 * 16384;
    const _Float16* WoutT_l = wb + (size_t)11 * 16384;

    const int NB = (N + 255) / 256;                   // 196 scan blocks
    const int EG = ((E + ECHUNK - 1) / ECHUNK) * 8;   // 2000 xcd-chunked blocks
    const int AG = ((N + NPB - 1) / NPB) * 8;         // 12504 aggregate blocks

    hipMemsetAsync(cnt, 0, N * sizeof(int), stream);
    hist_kernel<<<EG, 256, 0, stream>>>(src, cnt, E);
    scan1_kernel<<<NB, 256, 0, stream>>>(cnt, row_ptr, bsum, N);
    scan2_kernel<<<1, 256, 0, stream>>>(bsum, NB);
    scan3_kernel<<<NB, 256, 0, stream>>>(bsum, row_ptr, cursor, N, E);
    scatter_kernel<<<EG, 256, 0, stream>>>(src, dst, cursor, col, E);
    sortrows_kernel<<<(N + 3) / 4, 256, 0, stream>>>(row_ptr, col, N);
    conv_wt_kernel<<<(90112 + 255) / 256, 256, 0, stream>>>(W_in, W_self, W_neigh, W_out, wb);

    const int G = (N + 63) / 64;  // 782

    // h = x @ W_in + b_in
    gemm_mfma<128, false, true, false><<<G, 256, 0, stream>>>(
        x, nullptr, WinT_h, WinT_l, nullptr, nullptr, b_in, h, N);

    for (int i = 0; i < 2; i++) {
        maxk_kernel<<<(N + 3) / 4, 256, 0, stream>>>(h, hsc, N);
        aggregate_kernel<<<AG, 256, 0, stream>>>(hsc, row_ptr, col, agg, N);
        const _Float16* WsT_h = wb + (size_t)(2 + 2 * i) * 16384;
        const _Float16* WsT_l = wb + (size_t)(3 + 2 * i) * 16384;
        const _Float16* WnT_h = wb + (size_t)(6 + 2 * i) * 16384;
        const _Float16* WnT_l = wb + (size_t)(7 + 2 * i) * 16384;
        // h = hs @ W_self[i] + agg @ W_neigh[i]
        gemm_mfma<128, true, false, true><<<G, 256, 0, stream>>>(
            hsc, agg, WsT_h, WsT_l, WnT_h, WnT_l, nullptr, h, N);
    }

    // out = h @ W_out + b_out
    gemm_mfma<64, false, true, false><<<G, 256, 0, stream>>>(
        h, nullptr, WoutT_h, WoutT_l, nullptr, nullptr, b_out, (float*)d_out, N);
}

// Round 11
// 408.934 us; speedup vs baseline: 1.1024x; 1.1024x over previous
//
#include <hip/hip_runtime.h>

#define KDIM 128
#define NNODE 50000
#define CHSTRIDE 800000   // floats per chunk slab: 50000 nodes * 16 feats

typedef _Float16 f16x8 __attribute__((ext_vector_type(8)));
typedef _Float16 f16x4 __attribute__((ext_vector_type(4)));
typedef float f32x16 __attribute__((ext_vector_type(16)));

// ---------------------------------------------------------------------------
// CSR build. hist/scatter are XCD-chunked: block = (chunk<<3)|r, node-range r
// on (round-robin-dispatched) XCD r -> cnt/cursor atomics and col writes stay
// XCD-L2-local.
// ---------------------------------------------------------------------------
#define NRANGE 6250   // 50000 / 8
#define ECHUNK 3200   // edges per chunk; chunks = ceil(E/3200) = 250

__global__ void hist_kernel(const int* __restrict__ src, int* __restrict__ cnt, int E) {
    const int r = blockIdx.x & 7;
    const int chunk = blockIdx.x >> 3;
    const int lo = r * NRANGE, hi = lo + NRANGE;
    const int base = chunk * ECHUNK;
    const int end = min(base + ECHUNK, E);
    for (int i = base + threadIdx.x; i < end; i += 256) {
        int s = src[i];
        if (s >= lo && s < hi) atomicAdd(&cnt[s], 1);
    }
}

__global__ void scatter_kernel(const int* __restrict__ src, const int* __restrict__ dst,
                               int* cursor, int* __restrict__ col, int E) {
    const int r = blockIdx.x & 7;
    const int chunk = blockIdx.x >> 3;
    const int lo = r * NRANGE, hi = lo + NRANGE;
    const int base = chunk * ECHUNK;
    const int end = min(base + ECHUNK, E);
    for (int i = base + threadIdx.x; i < end; i += 256) {
        int s = src[i];
        if (s >= lo && s < hi) {
            int p = atomicAdd(&cursor[s], 1);
            col[p] = dst[i];
        }
    }
}

// Hierarchical exclusive scan of cnt[0..N) -> row_ptr, cursor (3 kernels).
__global__ void scan1_kernel(const int* __restrict__ cnt, int* __restrict__ row_ptr,
                             int* __restrict__ bsum, int N) {
    __shared__ int ws[4];
    const int t = threadIdx.x;
    const int lane = t & 63, w = t >> 6;
    const int i = blockIdx.x * 256 + t;
    int v = (i < N) ? cnt[i] : 0;
    int x = v;
    #pragma unroll
    for (int off = 1; off < 64; off <<= 1) {
        int u = __shfl_up(x, off);
        if (lane >= off) x += u;
    }
    if (lane == 63) ws[w] = x;
    __syncthreads();
    int wexcl = 0;
    #pragma unroll
    for (int k = 0; k < 4; k++) wexcl += (k < w) ? ws[k] : 0;
    if (i < N) row_ptr[i] = wexcl + x - v;      // block-local exclusive
    if (t == 255) bsum[blockIdx.x] = wexcl + x; // block total
}

__global__ void scan2_kernel(int* __restrict__ bsum, int NB) {
    __shared__ int ws[4];
    const int t = threadIdx.x;
    const int lane = t & 63, w = t >> 6;
    int v = (t < NB) ? bsum[t] : 0;
    int x = v;
    #pragma unroll
    for (int off = 1; off < 64; off <<= 1) {
        int u = __shfl_up(x, off);
        if (lane >= off) x += u;
    }
    if (lane == 63) ws[w] = x;
    __syncthreads();
    int wexcl = 0;
    #pragma unroll
    for (int k = 0; k < 4; k++) wexcl += (k < w) ? ws[k] : 0;
    if (t < NB) bsum[t] = wexcl + x - v;        // exclusive block offsets
}

__global__ void scan3_kernel(const int* __restrict__ bsum, int* __restrict__ row_ptr,
                             int* __restrict__ cursor, int N, int E) {
    const int i = blockIdx.x * 256 + threadIdx.x;
    if (i < N) {
        int v = row_ptr[i] + bsum[blockIdx.x];
        row_ptr[i] = v;
        cursor[i] = v;
    }
    if (i == 0) row_ptr[N] = E;
}

// Sort each CSR row's col values ascending -> deterministic summation order.
__global__ void sortrows_kernel(const int* __restrict__ row_ptr, int* __restrict__ col, int M) {
    int wid = (blockIdx.x * blockDim.x + threadIdx.x) >> 6;
    int lane = threadIdx.x & 63;
    if (wid >= M) return;
    int s = row_ptr[wid], e = row_ptr[wid + 1], len = e - s;
    if (len <= 1) return;
    if (len <= 64) {
        int v = (lane < len) ? col[s + lane] : 0x7fffffff;
        #pragma unroll
        for (int k = 2; k <= 64; k <<= 1) {
            #pragma unroll
            for (int j = k >> 1; j > 0; j >>= 1) {
                int o = __shfl_xor(v, j);
                bool dir = ((lane & k) == 0);
                bool smaller = ((lane & j) == 0);
                int mn = min(v, o), mx = max(v, o);
                v = (dir == smaller) ? mn : mx;
            }
        }
        if (lane < len) col[s + lane] = v;
    } else if (lane == 0) {
        for (int a = s + 1; a < e; a++) {
            int key = col[a];
            int b = a - 1;
            while (b >= s && col[b] > key) { col[b + 1] = col[b]; b--; }
            col[b + 1] = key;
        }
    }
}

// ---------------------------------------------------------------------------
// MaxK: keep top-32 of 128 per row (jax.lax.top_k tie-break: lower index wins)
// Writes hs in CHUNKED layout [chunk=f/16][node][16] (64B per node per chunk)
// so the aggregate gather is XCD-L2-resident per chunk.
// ---------------------------------------------------------------------------
__global__ void maxk_kernel(const float* __restrict__ h, float* __restrict__ hsc, int M) {
    int wid = (blockIdx.x * blockDim.x + threadIdx.x) >> 6;
    int lane = threadIdx.x & 63;
    if (wid >= M) return;
    float2 v = ((const float2*)(h + (size_t)wid * KDIM))[lane];

    unsigned int u0 = __float_as_uint(v.x);
    u0 = (u0 & 0x80000000u) ? ~u0 : (u0 | 0x80000000u);
    unsigned int u1 = __float_as_uint(v.y);
    u1 = (u1 & 0x80000000u) ? ~u1 : (u1 | 0x80000000u);

    unsigned int prefix = 0;
    int remaining = 32;
    #pragma unroll
    for (int b = 31; b >= 0; --b) {
        unsigned int candHi = (prefix >> b) | 1u;
        unsigned long long m0 = __ballot((u0 >> b) == candHi);
        unsigned long long m1 = __ballot((u1 >> b) == candHi);
        int cnt = __popcll(m0) + __popcll(m1);
        if (cnt >= remaining) prefix |= (1u << b);
        else remaining -= cnt;
    }

    unsigned long long e0 = __ballot(u0 == prefix);
    unsigned long long e1 = __ballot(u1 == prefix);
    unsigned long long g0 = __ballot(u0 > prefix);
    unsigned long long g1 = __ballot(u1 > prefix);
    int quota = 32 - (__popcll(g0) + __popcll(g1));
    unsigned long long below = (1ULL << lane) - 1ULL;
    int rank0 = __popcll(e0 & below) + __popcll(e1 & below);
    int rank1 = rank0 + (int)((e0 >> lane) & 1ULL);
    bool k0 = (u0 > prefix) || (((e0 >> lane) & 1ULL) && rank0 < quota);
    bool k1 = (u1 > prefix) || (((e1 >> lane) & 1ULL) && rank1 < quota);

    float2 o;
    o.x = k0 ? v.x : 0.0f;
    o.y = k1 ? v.y : 0.0f;
    // lane owns features 2l,2l+1 -> chunk = l>>3, float2 slot = l&7
    ((float2*)(hsc + (size_t)(lane >> 3) * CHSTRIDE))[(size_t)wid * 8 + (lane & 7)] = o;
}

// ---------------------------------------------------------------------------
// Aggregation (feature-chunked, lean): chunk c = blockIdx&7 -> one chunk per
// XCD (round-robin) so gathers hit the 3.2MB L2-resident slab. Block = 64
// consecutive nodes; their edges are one contiguous col-range (avg ~1024) ->
// staged once into LDS (coalesced), killing the per-iteration col VMEM chain.
// Wave = 1 node at a time (16/wave), lane = (e8 edge-slot, f2 feature-pair);
// per-lane base pointer -> gather addr is one lshl_add. Fixed shfl tree.
// ---------------------------------------------------------------------------
#define APB 64     // nodes per block
#define ECAP 2048  // LDS edge cap (block edge count ~N(1024,32^2); fallback if exceeded)

__global__ __launch_bounds__(256)
void aggregate_kernel(const float* __restrict__ hsc, const int* __restrict__ row_ptr,
                      const int* __restrict__ col, float* __restrict__ agg, int M) {
    __shared__ int cols[ECAP];
    const int c = blockIdx.x & 7;
    const int g = blockIdx.x >> 3;
    const int n0 = g * APB;
    const int nend = min(n0 + APB, M);
    const int tid = threadIdx.x;
    const int w = tid >> 6;
    const int lane = tid & 63;
    const int e8 = lane >> 3;
    const int f2 = lane & 7;

    const int base0 = row_ptr[n0];
    const int ecount = row_ptr[nend] - base0;
    const bool fits = (ecount <= ECAP);
    if (fits) {
        for (int i = tid; i < ecount; i += 256) cols[i] = col[base0 + i];
    }
    __syncthreads();

    const char* bp = (const char*)(hsc + (size_t)c * CHSTRIDE) + f2 * 8;

    const int nw0 = n0 + w * 16;
    const int nw1 = min(nw0 + 16, nend);
    if (fits) {
        for (int n = nw0; n < nw1; n++) {
            int s = row_ptr[n] - base0, e = row_ptr[n + 1] - base0;
            float ax0 = 0.f, ay0 = 0.f, ax1 = 0.f, ay1 = 0.f;
            int j = s + e8;
            for (; j + 8 < e; j += 16) {
                int c0 = cols[j];
                int c1 = cols[j + 8];
                float2 v0 = *(const float2*)(bp + ((size_t)c0 << 6));
                float2 v1 = *(const float2*)(bp + ((size_t)c1 << 6));
                ax0 += v0.x; ay0 += v0.y;
                ax1 += v1.x; ay1 += v1.y;
            }
            if (j < e) {
                float2 v = *(const float2*)(bp + ((size_t)cols[j] << 6));
                ax0 += v.x; ay0 += v.y;
            }
            float tx = ax0 + ax1, ty = ay0 + ay1;
            tx += __shfl_xor(tx, 8);  ty += __shfl_xor(ty, 8);
            tx += __shfl_xor(tx, 16); ty += __shfl_xor(ty, 16);
            tx += __shfl_xor(tx, 32); ty += __shfl_xor(ty, 32);
            if (e8 == 0) {
                float inv = 1.0f / ((float)(e - s) + 1e-6f);
                float2 o; o.x = tx * inv; o.y = ty * inv;
                ((float2*)(agg + (size_t)n * KDIM + c * 16))[f2] = o;
            }
        }
    } else {
        const int* cg = col + base0;
        for (int n = nw0; n < nw1; n++) {
            int s = row_ptr[n] - base0, e = row_ptr[n + 1] - base0;
            float ax0 = 0.f, ay0 = 0.f, ax1 = 0.f, ay1 = 0.f;
            int j = s + e8;
            for (; j + 8 < e; j += 16) {
                int c0 = cg[j];
                int c1 = cg[j + 8];
                float2 v0 = *(const float2*)(bp + ((size_t)c0 << 6));
                float2 v1 = *(const float2*)(bp + ((size_t)c1 << 6));
                ax0 += v0.x; ay0 += v0.y;
                ax1 += v1.x; ay1 += v1.y;
            }
            if (j < e) {
                float2 v = *(const float2*)(bp + ((size_t)cg[j] << 6));
                ax0 += v.x; ay0 += v.y;
            }
            float tx = ax0 + ax1, ty = ay0 + ay1;
            tx += __shfl_xor(tx, 8);  ty += __shfl_xor(ty, 8);
            tx += __shfl_xor(tx, 16); ty += __shfl_xor(ty, 16);
            tx += __shfl_xor(tx, 32); ty += __shfl_xor(ty, 32);
            if (e8 == 0) {
                float inv = 1.0f / ((float)(e - s) + 1e-6f);
                float2 o; o.x = tx * inv; o.y = ty * inv;
                ((float2*)(agg + (size_t)n * KDIM + c * 16))[f2] = o;
            }
        }
    }
}

// ---------------------------------------------------------------------------
// Weight prep: transpose to [n][k] and split f32 -> fp16 (hi, lo).
// ---------------------------------------------------------------------------
__global__ void conv_wt_kernel(const float* __restrict__ W_in,
                               const float* __restrict__ W_self,
                               const float* __restrict__ W_neigh,
                               const float* __restrict__ W_out,
                               _Float16* __restrict__ wb) {
    int t = blockIdx.x * blockDim.x + threadIdx.x;
    if (t < 81920) {
        int m = t >> 14;            // 0..4
        int e = t & 16383;
        int n = e >> 7, k = e & 127;
        const float* S = (m == 0) ? W_in
                       : (m <= 2) ? (W_self + (size_t)(m - 1) * 16384)
                                  : (W_neigh + (size_t)(m - 3) * 16384);
        float v = S[k * 128 + n];
        _Float16 hi = (_Float16)v;
        _Float16 lo = (_Float16)(v - (float)hi);
        int pair = m * 2;
        wb[(size_t)pair * 16384 + n * 128 + k] = hi;
        wb[(size_t)(pair + 1) * 16384 + n * 128 + k] = lo;
    } else if (t < 90112) {
        int e = t - 81920;          // [0, 8192)
        int n = e >> 7, k = e & 127;
        float v = W_out[k * 64 + n];
        _Float16 hi = (_Float16)v;
        _Float16 lo = (_Float16)(v - (float)hi);
        wb[(size_t)10 * 16384 + e] = hi;
        wb[(size_t)11 * 16384 + e] = lo;
    }
}

// ---------------------------------------------------------------------------
// Split-fp16 MFMA GEMM: C[M,BN] = A1 @ B1 (+ A2 @ B2) (+ bias), K=128, f32 I/O.
// a@b = hi@hi + hi@lo + lo@hi (lo@lo dropped, ~2^-22 rel).
// Sources staged SEQUENTIALLY through one 32 KB LDS buffer.
// A1CHUNK: A1 is in chunked layout [k/16][node][16] (hs from maxk).
// ---------------------------------------------------------------------------
template <int BN, bool DUAL, bool BIAS, bool A1CHUNK>
__global__ __launch_bounds__(256)
void gemm_mfma(const float* __restrict__ A1, const float* __restrict__ A2,
               const _Float16* __restrict__ B1h, const _Float16* __restrict__ B1l,
               const _Float16* __restrict__ B2h, const _Float16* __restrict__ B2l,
               const float* __restrict__ bias, float* __restrict__ C, int M) {
    constexpr int NSRC = DUAL ? 2 : 1;
    constexpr int NT = BN / 32;
    constexpr int TPW = NT / 2;

    __shared__ __align__(16) char Alds[2 * 64 * 256];  // 32 KB: [h/l][row][256B]

    const int tid = threadIdx.x;
    const int w = tid >> 6;
    const int lane = tid & 63;
    const int l31 = lane & 31;
    const int kslot = lane >> 5;
    const int row0 = blockIdx.x * 64;

    const int n0 = (BN == 128) ? w * 32 : (w & 1) * 32;
    const int mt0 = (BN == 128) ? 0 : (w >> 1);

    f32x16 acc[TPW];
    #pragma unroll
    for (int t = 0; t < TPW; t++)
        #pragma unroll
        for (int e = 0; e < 16; e++) acc[t][e] = 0.0f;

    for (int s = 0; s < NSRC; s++) {
        if (s) __syncthreads();   // previous source's MFMA reads done
        // ---- stage A_s: f32 -> (hi,lo) fp16 into swizzled LDS ----
        const float* A = s ? A2 : A1;
        #pragma unroll
        for (int p = 0; p < 8; p++) {
            int idx = tid + p * 256;
            int row = idx >> 5, k4 = idx & 31;
            float4 v = make_float4(0.f, 0.f, 0.f, 0.f);
            if (row0 + row < M) {
                if (A1CHUNK && s == 0)
                    v = *(const float4*)(A + (size_t)(k4 >> 2) * CHSTRIDE
                                           + (size_t)(row0 + row) * 16 + (k4 & 3) * 4);
                else
                    v = *(const float4*)(A + (size_t)(row0 + row) * KDIM + k4 * 4);
            }
            _Float16 h0 = (_Float16)v.x, h1 = (_Float16)v.y,
                     h2 = (_Float16)v.z, h3 = (_Float16)v.w;
            f16x4 hv = {h0, h1, h2, h3};
            f16x4 lv = {(_Float16)(v.x - (float)h0), (_Float16)(v.y - (float)h1),
                        (_Float16)(v.z - (float)h2), (_Float16)(v.w - (float)h3)};
            int boff = (k4 * 8) ^ ((row & 7) << 4);
            *(f16x4*)(Alds + row * 256 + boff) = hv;
            *(f16x4*)(Alds + 16384 + row * 256 + boff) = lv;
        }
        __syncthreads();

        // ---- K-loop ----
        const _Float16* Bh = s ? B2h : B1h;
        const _Float16* Bl = s ? B2l : B1l;
        const _Float16* bph = Bh + (size_t)(n0 + l31) * 128 + kslot * 8;
        const _Float16* bpl = Bl + (size_t)(n0 + l31) * 128 + kslot * 8;
        #pragma unroll
        for (int kb = 0; kb < 8; kb++) {
            f16x8 bh = *(const f16x8*)(bph + kb * 16);
            f16x8 bl = *(const f16x8*)(bpl + kb * 16);
            #pragma unroll
            for (int t = 0; t < TPW; t++) {
                int row = (mt0 + t) * 32 + l31;
                int boff = ((kb * 2 + kslot) * 16) ^ ((row & 7) << 4);
                const char* rp = Alds + row * 256 + boff;
                f16x8 ah = *(const f16x8*)(rp);
                f16x8 al = *(const f16x8*)(rp + 16384);
                acc[t] = __builtin_amdgcn_mfma_f32_32x32x16_f16(al, bh, acc[t], 0, 0, 0);
                acc[t] = __builtin_amdgcn_mfma_f32_32x32x16_f16(ah, bl, acc[t], 0, 0, 0);
                acc[t] = __builtin_amdgcn_mfma_f32_32x32x16_f16(ah, bh, acc[t], 0, 0, 0);
            }
        }
    }

    float bv = 0.0f;
    if (BIAS) bv = bias[n0 + l31];
    #pragma unroll
    for (int t = 0; t < TPW; t++) {
        #pragma unroll
        for (int r = 0; r < 16; r++) {
            int row = row0 + (mt0 + t) * 32 + (r & 3) + 8 * (r >> 2) + 4 * kslot;
            if (row < M) C[(size_t)row * BN + n0 + l31] = acc[t][r] + bv;
        }
    }
}

// ---------------------------------------------------------------------------
extern "C" void kernel_launch(void* const* d_in, const int* in_sizes, int n_in,
                              void* d_out, int out_size, void* d_ws, size_t ws_size,
                              hipStream_t stream) {
    const float* x       = (const float*)d_in[0];
    const float* W_in    = (const float*)d_in[1];
    const float* b_in    = (const float*)d_in[2];
    const float* W_self  = (const float*)d_in[3];
    const float* W_neigh = (const float*)d_in[4];
    const float* W_out   = (const float*)d_in[5];
    const float* b_out   = (const float*)d_in[6];
    const int*   eidx    = (const int*)d_in[7];

    const int N = NNODE, E = 800000;
    const int* src = eidx;
    const int* dst = eidx + E;

    char* ws = (char*)d_ws;
    float* h   = (float*)(ws);                  // 25.6 MB
    float* hsc = (float*)(ws + 25600000);       // 25.6 MB (chunked [8][N][16])
    float* agg = (float*)(ws + 51200000);       // 25.6 MB
    int* cnt     = (int*)(ws + 76800000);       // 200 KB
    int* row_ptr = (int*)(ws + 77000000);       // 200 KB
    int* cursor  = (int*)(ws + 77200016);       // 200 KB
    int* col     = (int*)(ws + 77400016);       // 3.2 MB
    _Float16* wb = (_Float16*)(ws + 80600016);  // 384 KB weight slots
    int* bsum    = (int*)(ws + 81000016);       // 1 KB scan block sums

    const _Float16* WinT_h  = wb + (size_t)0 * 16384;
    const _Float16* WinT_l  = wb + (size_t)1 * 16384;
    const _Float16* WoutT_h = wb + (size_t)10 * 16384;
    const _Float16* WoutT_l = wb + (size_t)11 * 16384;

    const int NB = (N + 255) / 256;                   // 196 scan blocks
    const int EG = ((E + ECHUNK - 1) / ECHUNK) * 8;   // 2000 xcd-chunked blocks
    const int AG = ((N + APB - 1) / APB) * 8;         // 6256 aggregate blocks

    hipMemsetAsync(cnt, 0, N * sizeof(int), stream);
    hist_kernel<<<EG, 256, 0, stream>>>(src, cnt, E);
    scan1_kernel<<<NB, 256, 0, stream>>>(cnt, row_ptr, bsum, N);
    scan2_kernel<<<1, 256, 0, stream>>>(bsum, NB);
    scan3_kernel<<<NB, 256, 0, stream>>>(bsum, row_ptr, cursor, N, E);
    scatter_kernel<<<EG, 256, 0, stream>>>(src, dst, cursor, col, E);
    sortrows_kernel<<<(N + 3) / 4, 256, 0, stream>>>(row_ptr, col, N);
    conv_wt_kernel<<<(90112 + 255) / 256, 256, 0, stream>>>(W_in, W_self, W_neigh, W_out, wb);

    const int G = (N + 63) / 64;  // 782

    // h = x @ W_in + b_in
    gemm_mfma<128, false, true, false><<<G, 256, 0, stream>>>(
        x, nullptr, WinT_h, WinT_l, nullptr, nullptr, b_in, h, N);

    for (int i = 0; i < 2; i++) {
        maxk_kernel<<<(N + 3) / 4, 256, 0, stream>>>(h, hsc, N);
        aggregate_kernel<<<AG, 256, 0, stream>>>(hsc, row_ptr, col, agg, N);
        const _Float16* WsT_h = wb + (size_t)(2 + 2 * i) * 16384;
        const _Float16* WsT_l = wb + (size_t)(3 + 2 * i) * 16384;
        const _Float16* WnT_h = wb + (size_t)(6 + 2 * i) * 16384;
        const _Float16* WnT_l = wb + (size_t)(7 + 2 * i) * 16384;
        // h = hs @ W_self[i] + agg @ W_neigh[i]
        gemm_mfma<128, true, false, true><<<G, 256, 0, stream>>>(
            hsc, agg, WsT_h, WsT_l, WnT_h, WnT_l, nullptr, h, N);
    }

    // out = h @ W_out + b_out
    gemm_mfma<64, false, true, false><<<G, 256, 0, stream>>>(
        h, nullptr, WoutT_h, WoutT_l, nullptr, nullptr, b_out, (float*)d_out, N);
}

// Round 12
// 368.930 us; speedup vs baseline: 1.2220x; 1.1084x over previous
//
#include <hip/hip_runtime.h>

#define KDIM 128
#define NNODE 50000
#define CHSTRIDE 800000   // floats per chunk slab: 50000 nodes * 16 feats

typedef _Float16 f16x8 __attribute__((ext_vector_type(8)));
typedef _Float16 f16x4 __attribute__((ext_vector_type(4)));
typedef float f32x16 __attribute__((ext_vector_type(16)));

// ---------------------------------------------------------------------------
// CSR build. hist/scatter are XCD-chunked: block = (chunk<<3)|r, node-range r
// on (round-robin-dispatched) XCD r -> cnt/cursor atomics and col writes stay
// XCD-L2-local.
// ---------------------------------------------------------------------------
#define NRANGE 6250   // 50000 / 8
#define ECHUNK 3200   // edges per chunk; chunks = ceil(E/3200) = 250

__global__ void hist_kernel(const int* __restrict__ src, int* __restrict__ cnt, int E) {
    const int r = blockIdx.x & 7;
    const int chunk = blockIdx.x >> 3;
    const int lo = r * NRANGE, hi = lo + NRANGE;
    const int base = chunk * ECHUNK;
    const int end = min(base + ECHUNK, E);
    for (int i = base + threadIdx.x; i < end; i += 256) {
        int s = src[i];
        if (s >= lo && s < hi) atomicAdd(&cnt[s], 1);
    }
}

__global__ void scatter_kernel(const int* __restrict__ src, const int* __restrict__ dst,
                               int* cursor, int* __restrict__ col, int E) {
    const int r = blockIdx.x & 7;
    const int chunk = blockIdx.x >> 3;
    const int lo = r * NRANGE, hi = lo + NRANGE;
    const int base = chunk * ECHUNK;
    const int end = min(base + ECHUNK, E);
    for (int i = base + threadIdx.x; i < end; i += 256) {
        int s = src[i];
        if (s >= lo && s < hi) {
            int p = atomicAdd(&cursor[s], 1);
            col[p] = dst[i];
        }
    }
}

// Hierarchical exclusive scan of cnt[0..N) -> row_ptr, cursor (3 kernels).
__global__ void scan1_kernel(const int* __restrict__ cnt, int* __restrict__ row_ptr,
                             int* __restrict__ bsum, int N) {
    __shared__ int ws[4];
    const int t = threadIdx.x;
    const int lane = t & 63, w = t >> 6;
    const int i = blockIdx.x * 256 + t;
    int v = (i < N) ? cnt[i] : 0;
    int x = v;
    #pragma unroll
    for (int off = 1; off < 64; off <<= 1) {
        int u = __shfl_up(x, off);
        if (lane >= off) x += u;
    }
    if (lane == 63) ws[w] = x;
    __syncthreads();
    int wexcl = 0;
    #pragma unroll
    for (int k = 0; k < 4; k++) wexcl += (k < w) ? ws[k] : 0;
    if (i < N) row_ptr[i] = wexcl + x - v;      // block-local exclusive
    if (t == 255) bsum[blockIdx.x] = wexcl + x; // block total
}

__global__ void scan2_kernel(int* __restrict__ bsum, int NB) {
    __shared__ int ws[4];
    const int t = threadIdx.x;
    const int lane = t & 63, w = t >> 6;
    int v = (t < NB) ? bsum[t] : 0;
    int x = v;
    #pragma unroll
    for (int off = 1; off < 64; off <<= 1) {
        int u = __shfl_up(x, off);
        if (lane >= off) x += u;
    }
    if (lane == 63) ws[w] = x;
    __syncthreads();
    int wexcl = 0;
    #pragma unroll
    for (int k = 0; k < 4; k++) wexcl += (k < w) ? ws[k] : 0;
    if (t < NB) bsum[t] = wexcl + x - v;        // exclusive block offsets
}

__global__ void scan3_kernel(const int* __restrict__ bsum, int* __restrict__ row_ptr,
                             int* __restrict__ cursor, int N, int E) {
    const int i = blockIdx.x * 256 + threadIdx.x;
    if (i < N) {
        int v = row_ptr[i] + bsum[blockIdx.x];
        row_ptr[i] = v;
        cursor[i] = v;
    }
    if (i == 0) row_ptr[N] = E;
}

// Sort each CSR row's col values ascending -> deterministic summation order.
__global__ void sortrows_kernel(const int* __restrict__ row_ptr, int* __restrict__ col, int M) {
    int wid = (blockIdx.x * blockDim.x + threadIdx.x) >> 6;
    int lane = threadIdx.x & 63;
    if (wid >= M) return;
    int s = row_ptr[wid], e = row_ptr[wid + 1], len = e - s;
    if (len <= 1) return;
    if (len <= 64) {
        int v = (lane < len) ? col[s + lane] : 0x7fffffff;
        #pragma unroll
        for (int k = 2; k <= 64; k <<= 1) {
            #pragma unroll
            for (int j = k >> 1; j > 0; j >>= 1) {
                int o = __shfl_xor(v, j);
                bool dir = ((lane & k) == 0);
                bool smaller = ((lane & j) == 0);
                int mn = min(v, o), mx = max(v, o);
                v = (dir == smaller) ? mn : mx;
            }
        }
        if (lane < len) col[s + lane] = v;
    } else if (lane == 0) {
        for (int a = s + 1; a < e; a++) {
            int key = col[a];
            int b = a - 1;
            while (b >= s && col[b] > key) { col[b + 1] = col[b]; b--; }
            col[b + 1] = key;
        }
    }
}

// ---------------------------------------------------------------------------
// MaxK: keep top-32 of 128 per row (jax.lax.top_k tie-break: lower index wins)
// Writes hs in CHUNKED layout [chunk=f/16][node][16] (64B per node per chunk)
// so the aggregate gather is XCD-L2-resident per chunk.
// ---------------------------------------------------------------------------
__global__ void maxk_kernel(const float* __restrict__ h, float* __restrict__ hsc, int M) {
    int wid = (blockIdx.x * blockDim.x + threadIdx.x) >> 6;
    int lane = threadIdx.x & 63;
    if (wid >= M) return;
    float2 v = ((const float2*)(h + (size_t)wid * KDIM))[lane];

    unsigned int u0 = __float_as_uint(v.x);
    u0 = (u0 & 0x80000000u) ? ~u0 : (u0 | 0x80000000u);
    unsigned int u1 = __float_as_uint(v.y);
    u1 = (u1 & 0x80000000u) ? ~u1 : (u1 | 0x80000000u);

    unsigned int prefix = 0;
    int remaining = 32;
    #pragma unroll
    for (int b = 31; b >= 0; --b) {
        unsigned int candHi = (prefix >> b) | 1u;
        unsigned long long m0 = __ballot((u0 >> b) == candHi);
        unsigned long long m1 = __ballot((u1 >> b) == candHi);
        int cnt = __popcll(m0) + __popcll(m1);
        if (cnt >= remaining) prefix |= (1u << b);
        else remaining -= cnt;
    }

    unsigned long long e0 = __ballot(u0 == prefix);
    unsigned long long e1 = __ballot(u1 == prefix);
    unsigned long long g0 = __ballot(u0 > prefix);
    unsigned long long g1 = __ballot(u1 > prefix);
    int quota = 32 - (__popcll(g0) + __popcll(g1));
    unsigned long long below = (1ULL << lane) - 1ULL;
    int rank0 = __popcll(e0 & below) + __popcll(e1 & below);
    int rank1 = rank0 + (int)((e0 >> lane) & 1ULL);
    bool k0 = (u0 > prefix) || (((e0 >> lane) & 1ULL) && rank0 < quota);
    bool k1 = (u1 > prefix) || (((e1 >> lane) & 1ULL) && rank1 < quota);

    float2 o;
    o.x = k0 ? v.x : 0.0f;
    o.y = k1 ? v.y : 0.0f;
    // lane owns features 2l,2l+1 -> chunk = l>>3, float2 slot = l&7
    ((float2*)(hsc + (size_t)(lane >> 3) * CHSTRIDE))[(size_t)wid * 8 + (lane & 7)] = o;
}

// ---------------------------------------------------------------------------
// Aggregation (feature-chunked, 4 nodes/wave): chunk c = blockIdx&7 -> one
// chunk per XCD (round-robin) so gathers hit the 3.2MB L2-resident slab.
// Block = 16 nodes (4 waves x 4 nodes); block's edges = contiguous col range
// (~256) staged once into LDS. Lane = (ng node, e2 edge-slot, f2 feat-pair):
// per-node reduce is ONE shfl (xor 8); 2-unroll keeps 16 independent 64B
// gathers in flight per wave-iteration; 32-bit gather offsets.
// Deterministic: fixed chain order (a: j=s+e2+4t, b: +2; tail->a), a+b, e2-pair.
// ---------------------------------------------------------------------------
#define ANPB 16    // nodes per block
#define AECAP 1024 // LDS edge cap (block edges ~N(256,16^2); exact fallback)

__global__ __launch_bounds__(256)
void aggregate_kernel(const float* __restrict__ hsc, const int* __restrict__ row_ptr,
                      const int* __restrict__ col, float* __restrict__ agg, int M) {
    __shared__ int cols[AECAP];
    const int c = blockIdx.x & 7;
    const int g = blockIdx.x >> 3;
    const int n0 = g * ANPB;
    const int tid = threadIdx.x;
    const int w = tid >> 6;
    const int lane = tid & 63;
    const int ng = lane >> 4;        // node within wave: 0..3
    const int e2 = (lane >> 3) & 1;  // edge slot
    const int f2 = lane & 7;         // feature pair

    const int nend = min(n0 + ANPB, M);
    const int base0 = row_ptr[n0];
    const int ecount = row_ptr[nend] - base0;
    const bool fits = (ecount <= AECAP);
    if (fits) {
        for (int i = tid; i < ecount; i += 256) cols[i] = col[base0 + i];
    }
    __syncthreads();

    const int n = n0 + w * 4 + ng;
    const bool valid = (n < M);
    const int s = valid ? (row_ptr[n] - base0) : 0;
    const int e = valid ? (row_ptr[n + 1] - base0) : 0;
    const char* bp = (const char*)(hsc + (size_t)c * CHSTRIDE) + f2 * 8;

    float ax = 0.f, ay = 0.f, bx = 0.f, by = 0.f;
    int j = s + e2;
    if (fits) {
        for (; j + 2 < e; j += 4) {
            unsigned o0 = (unsigned)cols[j] << 6;
            unsigned o1 = (unsigned)cols[j + 2] << 6;
            float2 v0 = *(const float2*)(bp + o0);
            float2 v1 = *(const float2*)(bp + o1);
            ax += v0.x; ay += v0.y;
            bx += v1.x; by += v1.y;
        }
        if (j < e) {
            float2 v = *(const float2*)(bp + ((unsigned)cols[j] << 6));
            ax += v.x; ay += v.y;
        }
    } else {
        const int* cg = col + base0;
        for (; j + 2 < e; j += 4) {
            unsigned o0 = (unsigned)cg[j] << 6;
            unsigned o1 = (unsigned)cg[j + 2] << 6;
            float2 v0 = *(const float2*)(bp + o0);
            float2 v1 = *(const float2*)(bp + o1);
            ax += v0.x; ay += v0.y;
            bx += v1.x; by += v1.y;
        }
        if (j < e) {
            float2 v = *(const float2*)(bp + ((unsigned)cg[j] << 6));
            ax += v.x; ay += v.y;
        }
    }

    float tx = ax + bx, ty = ay + by;
    tx += __shfl_xor(tx, 8);
    ty += __shfl_xor(ty, 8);
    if (valid && e2 == 0) {
        float inv = 1.0f / ((float)(e - s) + 1e-6f);
        float2 o;
        o.x = tx * inv;
        o.y = ty * inv;
        ((float2*)(agg + (size_t)n * KDIM + c * 16))[f2] = o;
    }
}

// ---------------------------------------------------------------------------
// Weight prep: transpose to [n][k] and split f32 -> fp16 (hi, lo).
// ---------------------------------------------------------------------------
__global__ void conv_wt_kernel(const float* __restrict__ W_in,
                               const float* __restrict__ W_self,
                               const float* __restrict__ W_neigh,
                               const float* __restrict__ W_out,
                               _Float16* __restrict__ wb) {
    int t = blockIdx.x * blockDim.x + threadIdx.x;
    if (t < 81920) {
        int m = t >> 14;            // 0..4
        int e = t & 16383;
        int n = e >> 7, k = e & 127;
        const float* S = (m == 0) ? W_in
                       : (m <= 2) ? (W_self + (size_t)(m - 1) * 16384)
                                  : (W_neigh + (size_t)(m - 3) * 16384);
        float v = S[k * 128 + n];
        _Float16 hi = (_Float16)v;
        _Float16 lo = (_Float16)(v - (float)hi);
        int pair = m * 2;
        wb[(size_t)pair * 16384 + n * 128 + k] = hi;
        wb[(size_t)(pair + 1) * 16384 + n * 128 + k] = lo;
    } else if (t < 90112) {
        int e = t - 81920;          // [0, 8192)
        int n = e >> 7, k = e & 127;
        float v = W_out[k * 64 + n];
        _Float16 hi = (_Float16)v;
        _Float16 lo = (_Float16)(v - (float)hi);
        wb[(size_t)10 * 16384 + e] = hi;
        wb[(size_t)11 * 16384 + e] = lo;
    }
}

// ---------------------------------------------------------------------------
// Split-fp16 MFMA GEMM: C[M,BN] = A1 @ B1 (+ A2 @ B2) (+ bias), K=128, f32 I/O.
// a@b = hi@hi + hi@lo + lo@hi (lo@lo dropped, ~2^-22 rel).
// Sources staged SEQUENTIALLY through one 32 KB LDS buffer.
// A1CHUNK: A1 is in chunked layout [k/16][node][16] (hs from maxk).
// ---------------------------------------------------------------------------
template <int BN, bool DUAL, bool BIAS, bool A1CHUNK>
__global__ __launch_bounds__(256)
void gemm_mfma(const float* __restrict__ A1, const float* __restrict__ A2,
               const _Float16* __restrict__ B1h, const _Float16* __restrict__ B1l,
               const _Float16* __restrict__ B2h, const _Float16* __restrict__ B2l,
               const float* __restrict__ bias, float* __restrict__ C, int M) {
    constexpr int NSRC = DUAL ? 2 : 1;
    constexpr int NT = BN / 32;
    constexpr int TPW = NT / 2;

    __shared__ __align__(16) char Alds[2 * 64 * 256];  // 32 KB: [h/l][row][256B]

    const int tid = threadIdx.x;
    const int w = tid >> 6;
    const int lane = tid & 63;
    const int l31 = lane & 31;
    const int kslot = lane >> 5;
    const int row0 = blockIdx.x * 64;

    const int n0 = (BN == 128) ? w * 32 : (w & 1) * 32;
    const int mt0 = (BN == 128) ? 0 : (w >> 1);

    f32x16 acc[TPW];
    #pragma unroll
    for (int t = 0; t < TPW; t++)
        #pragma unroll
        for (int e = 0; e < 16; e++) acc[t][e] = 0.0f;

    for (int s = 0; s < NSRC; s++) {
        if (s) __syncthreads();   // previous source's MFMA reads done
        // ---- stage A_s: f32 -> (hi,lo) fp16 into swizzled LDS ----
        const float* A = s ? A2 : A1;
        #pragma unroll
        for (int p = 0; p < 8; p++) {
            int idx = tid + p * 256;
            int row = idx >> 5, k4 = idx & 31;
            float4 v = make_float4(0.f, 0.f, 0.f, 0.f);
            if (row0 + row < M) {
                if (A1CHUNK && s == 0)
                    v = *(const float4*)(A + (size_t)(k4 >> 2) * CHSTRIDE
                                           + (size_t)(row0 + row) * 16 + (k4 & 3) * 4);
                else
                    v = *(const float4*)(A + (size_t)(row0 + row) * KDIM + k4 * 4);
            }
            _Float16 h0 = (_Float16)v.x, h1 = (_Float16)v.y,
                     h2 = (_Float16)v.z, h3 = (_Float16)v.w;
            f16x4 hv = {h0, h1, h2, h3};
            f16x4 lv = {(_Float16)(v.x - (float)h0), (_Float16)(v.y - (float)h1),
                        (_Float16)(v.z - (float)h2), (_Float16)(v.w - (float)h3)};
            int boff = (k4 * 8) ^ ((row & 7) << 4);
            *(f16x4*)(Alds + row * 256 + boff) = hv;
            *(f16x4*)(Alds + 16384 + row * 256 + boff) = lv;
        }
        __syncthreads();

        // ---- K-loop ----
        const _Float16* Bh = s ? B2h : B1h;
        const _Float16* Bl = s ? B2l : B1l;
        const _Float16* bph = Bh + (size_t)(n0 + l31) * 128 + kslot * 8;
        const _Float16* bpl = Bl + (size_t)(n0 + l31) * 128 + kslot * 8;
        #pragma unroll
        for (int kb = 0; kb < 8; kb++) {
            f16x8 bh = *(const f16x8*)(bph + kb * 16);
            f16x8 bl = *(const f16x8*)(bpl + kb * 16);
            #pragma unroll
            for (int t = 0; t < TPW; t++) {
                int row = (mt0 + t) * 32 + l31;
                int boff = ((kb * 2 + kslot) * 16) ^ ((row & 7) << 4);
                const char* rp = Alds + row * 256 + boff;
                f16x8 ah = *(const f16x8*)(rp);
                f16x8 al = *(const f16x8*)(rp + 16384);
                acc[t] = __builtin_amdgcn_mfma_f32_32x32x16_f16(al, bh, acc[t], 0, 0, 0);
                acc[t] = __builtin_amdgcn_mfma_f32_32x32x16_f16(ah, bl, acc[t], 0, 0, 0);
                acc[t] = __builtin_amdgcn_mfma_f32_32x32x16_f16(ah, bh, acc[t], 0, 0, 0);
            }
        }
    }

    float bv = 0.0f;
    if (BIAS) bv = bias[n0 + l31];
    #pragma unroll
    for (int t = 0; t < TPW; t++) {
        #pragma unroll
        for (int r = 0; r < 16; r++) {
            int row = row0 + (mt0 + t) * 32 + (r & 3) + 8 * (r >> 2) + 4 * kslot;
            if (row < M) C[(size_t)row * BN + n0 + l31] = acc[t][r] + bv;
        }
    }
}

// ---------------------------------------------------------------------------
extern "C" void kernel_launch(void* const* d_in, const int* in_sizes, int n_in,
                              void* d_out, int out_size, void* d_ws, size_t ws_size,
                              hipStream_t stream) {
    const float* x       = (const float*)d_in[0];
    const float* W_in    = (const float*)d_in[1];
    const float* b_in    = (const float*)d_in[2];
    const float* W_self  = (const float*)d_in[3];
    const float* W_neigh = (const float*)d_in[4];
    const float* W_out   = (const float*)d_in[5];
    const float* b_out   = (const float*)d_in[6];
    const int*   eidx    = (const int*)d_in[7];

    const int N = NNODE, E = 800000;
    const int* src = eidx;
    const int* dst = eidx + E;

    char* ws = (char*)d_ws;
    float* h   = (float*)(ws);                  // 25.6 MB
    float* hsc = (float*)(ws + 25600000);       // 25.6 MB (chunked [8][N][16])
    float* agg = (float*)(ws + 51200000);       // 25.6 MB
    int* cnt     = (int*)(ws + 76800000);       // 200 KB
    int* row_ptr = (int*)(ws + 77000000);       // 200 KB
    int* cursor  = (int*)(ws + 77200016);       // 200 KB
    int* col     = (int*)(ws + 77400016);       // 3.2 MB
    _Float16* wb = (_Float16*)(ws + 80600016);  // 384 KB weight slots
    int* bsum    = (int*)(ws + 81000016);       // 1 KB scan block sums

    const _Float16* WinT_h  = wb + (size_t)0 * 16384;
    const _Float16* WinT_l  = wb + (size_t)1 * 16384;
    const _Float16* WoutT_h = wb + (size_t)10 * 16384;
    const _Float16* WoutT_l = wb + (size_t)11 * 16384;

    const int NB = (N + 255) / 256;                   // 196 scan blocks
    const int EG = ((E + ECHUNK - 1) / ECHUNK) * 8;   // 2000 xcd-chunked blocks
    const int AG = ((N + ANPB - 1) / ANPB) * 8;       // 25000 aggregate blocks

    hipMemsetAsync(cnt, 0, N * sizeof(int), stream);
    hist_kernel<<<EG, 256, 0, stream>>>(src, cnt, E);
    scan1_kernel<<<NB, 256, 0, stream>>>(cnt, row_ptr, bsum, N);
    scan2_kernel<<<1, 256, 0, stream>>>(bsum, NB);
    scan3_kernel<<<NB, 256, 0, stream>>>(bsum, row_ptr, cursor, N, E);
    scatter_kernel<<<EG, 256, 0, stream>>>(src, dst, cursor, col, E);
    sortrows_kernel<<<(N + 3) / 4, 256, 0, stream>>>(row_ptr, col, N);
    conv_wt_kernel<<<(90112 + 255) / 256, 256, 0, stream>>>(W_in, W_self, W_neigh, W_out, wb);

    const int G = (N + 63) / 64;  // 782

    // h = x @ W_in + b_in
    gemm_mfma<128, false, true, false><<<G, 256, 0, stream>>>(
        x, nullptr, WinT_h, WinT_l, nullptr, nullptr, b_in, h, N);

    for (int i = 0; i < 2; i++) {
        maxk_kernel<<<(N + 3) / 4, 256, 0, stream>>>(h, hsc, N);
        aggregate_kernel<<<AG, 256, 0, stream>>>(hsc, row_ptr, col, agg, N);
        const _Float16* WsT_h = wb + (size_t)(2 + 2 * i) * 16384;
        const _Float16* WsT_l = wb + (size_t)(3 + 2 * i) * 16384;
        const _Float16* WnT_h = wb + (size_t)(6 + 2 * i) * 16384;
        const _Float16* WnT_l = wb + (size_t)(7 + 2 * i) * 16384;
        // h = hs @ W_self[i] + agg @ W_neigh[i]
        gemm_mfma<128, true, false, true><<<G, 256, 0, stream>>>(
            hsc, agg, WsT_h, WsT_l, WnT_h, WnT_l, nullptr, h, N);
    }

    // out = h @ W_out + b_out
    gemm_mfma<64, false, true, false><<<G, 256, 0, stream>>>(
        h, nullptr, WoutT_h, WoutT_l, nullptr, nullptr, b_out, (float*)d_out, N);
}